// Round 3
// baseline (123.398 us; speedup 1.0000x reference)
//
#include <hip/hip_runtime.h>

// Problem constants (match the JAX reference)
constexpr int BATCH      = 256;
constexpr int T          = 100;
constexpr int J          = 32;
constexpr int EDGES      = 101;
constexpr int NBINS      = 100;
constexpr int NPOINTS    = T * J;          // 3200 points per row
constexpr int ROW_FLOATS = NPOINTS * 3;    // 9600 floats per row
constexpr int NREP       = 32;             // histogram replicas
constexpr int HSTRIDE    = 101;            // replica stride (101*4B: 5r+b mod 32 spans banks)
constexpr int NTHREADS   = 1024;
constexpr int NWAVES     = NTHREADS / 64;  // 16
constexpr int TMAIN      = 96;             // 6 exact rounds x 16 waves
constexpr float EPSF     = 1e-8f;
constexpr float NTOT     = 102400.0f;      // T*J*J = counts.sum()

// Exact searchsorted(edges, x, side='right') - 1, clipped to [0, NBINS-1].
// Edges recomputed in registers: edge(i) = mx * ((float)i * 0.01f) — bitwise
// identical to the stored construction for i in [1,99] (same two RN ops).
// Guess via approximate inverse width, exact fixup. i never probes edge 0/100.
__device__ __forceinline__ int bin_of(float x, float mx, float invw) {
    int i = (int)(x * invw);
    i = i < 0 ? 0 : (i > NBINS - 1 ? NBINS - 1 : i);
    while (i < NBINS - 1 && x >= __fmul_rn(mx, __fmul_rn((float)(i + 1), 0.01f))) ++i;
    while (i > 0 && x < __fmul_rn(mx, __fmul_rn((float)i, 0.01f))) --i;
    return i;
}

__global__ __launch_bounds__(NTHREADS)
void jsd_kernel(const float* __restrict__ g1all,
                const float* __restrict__ g2all,
                float* __restrict__ out)
{
#pragma clang fp contract(off)
    __shared__ float4 pts[2][NPOINTS];               // 102,400 B (16B/point: conflict-free b128)
    __shared__ unsigned int hist[2][NREP][HSTRIDE];  //  25,856 B
    __shared__ float sred[NWAVES];
    __shared__ float sterm[NBINS];
    __shared__ float edg[EDGES];
    __shared__ float s_mx, s_invw;

    const int tid  = threadIdx.x;
    const int row  = blockIdx.x;
    const int wid  = tid >> 6;
    const int lane = tid & 63;
    const int ds   = lane >> 5;   // dataset handled by this lane
    const int a    = lane & 31;   // "own" point index within a timestep

    const float* g1 = g1all + (size_t)row * ROW_FLOATS;
    const float* g2 = g2all + (size_t)row * ROW_FLOATS;

    // ---- Stage both rows into LDS as float4 (pad w), zero histograms.
    for (int k = tid; k < NPOINTS; k += NTHREADS) {
        pts[0][k] = make_float4(g1[3 * k + 0], g1[3 * k + 1], g1[3 * k + 2], 0.0f);
        pts[1][k] = make_float4(g2[3 * k + 0], g2[3 * k + 1], g2[3 * k + 2], 0.0f);
    }
    for (int k = tid; k < 2 * NREP * HSTRIDE; k += NTHREADS)
        (&hist[0][0][0])[k] = 0u;
    __syncthreads();

    const float4* __restrict__ P = pts[ds];

    // ---- Pass A: max squared distance (sqrt monotone => sqrt(max)).
    // Rotation enumeration: lane a vs (a+k)&31, k=1..16 (k=16 duplicated, max-safe).
    float vmax = 0.0f;
    for (int r = 0; r < TMAIN / NWAVES; ++r) {
        const int base = (wid + r * NWAVES) * J;
        const float4 o = P[base + a];
#pragma unroll
        for (int k = 1; k <= 16; ++k) {
            const float4 c = P[base + ((a + k) & 31)];
            float dx = o.x - c.x;
            float dy = o.y - c.y;
            float dz = o.z - c.z;
            float s  = dx * dx + dy * dy + dz * dz;   // ((x^2+y^2)+z^2), no FMA
            vmax = fmaxf(vmax, s);
        }
    }
    // Tail: 4 timesteps x 16 k = 64 (t,k) items, 4 per wave — balanced.
#pragma unroll
    for (int j = 0; j < 4; ++j) {
        const int it = wid * 4 + j;
        const int base = (TMAIN + (it >> 4)) * J;
        const int k = (it & 15) + 1;
        const float4 o = P[base + a];
        const float4 c = P[base + ((a + k) & 31)];
        float dx = o.x - c.x;
        float dy = o.y - c.y;
        float dz = o.z - c.z;
        vmax = fmaxf(vmax, dx * dx + dy * dy + dz * dz);
    }
    for (int off = 32; off > 0; off >>= 1)
        vmax = fmaxf(vmax, __shfl_down(vmax, off, 64));
    if (lane == 0) sred[wid] = vmax;
    __syncthreads();
    if (tid == 0) {
        float m = sred[0];
        for (int w = 1; w < NWAVES; ++w) m = fmaxf(m, sred[w]);
        float mx = __fsqrt_rn(m);
        s_mx = mx;
        s_invw = 100.0f / mx;   // guess only — bin_of fixup is exact
    }
    __syncthreads();
    const float mx   = s_mx;
    const float invw = s_invw;

    // edges[i] = mn*w0 + mx*w1 with mn==0 exactly (diagonal pairs) -> mx*w1[i];
    // w1[i] = (float)i * 0.01f (f32 linspace), endpoint pinned to 1.0.
    if (tid < EDGES) {
        float w1 = (tid == EDGES - 1) ? 1.0f : ((float)tid * 0.01f);
        edg[tid] = mx * w1;
    }

    // ---- Pass B: recompute distances, histogram.
    // k<16: unordered pair counted once -> weight 2. k==16: both sides count -> weight 1.
    unsigned int* __restrict__ H = &hist[ds][a][0];
    for (int r = 0; r < TMAIN / NWAVES; ++r) {
        const int base = (wid + r * NWAVES) * J;
        const float4 o = P[base + a];
#pragma unroll
        for (int k = 1; k <= 16; ++k) {
            const float4 c = P[base + ((a + k) & 31)];
            float dx = o.x - c.x;
            float dy = o.y - c.y;
            float dz = o.z - c.z;
            float s  = dx * dx + dy * dy + dz * dz;
            float x  = __fsqrt_rn(s);
            atomicAdd(&H[bin_of(x, mx, invw)], (k < 16) ? 2u : 1u);
        }
    }
#pragma unroll
    for (int j = 0; j < 4; ++j) {
        const int it = wid * 4 + j;
        const int base = (TMAIN + (it >> 4)) * J;
        const int k = (it & 15) + 1;
        const float4 o = P[base + a];
        const float4 c = P[base + ((a + k) & 31)];
        float dx = o.x - c.x;
        float dy = o.y - c.y;
        float dz = o.z - c.z;
        float s  = dx * dx + dy * dy + dz * dz;
        float x  = __fsqrt_rn(s);
        atomicAdd(&H[bin_of(x, mx, invw)], (k < 16) ? 2u : 1u);
    }
    __syncthreads();

    // ---- Final: densities + JSD terms per bin; serial 100-add sum (bit-exact).
    if (tid < NBINS) {
        unsigned int c1 = 0, c2 = 0;
        for (int r = 0; r < NREP; ++r) { c1 += hist[0][r][tid]; c2 += hist[1][r][tid]; }
        if (tid == 0) { c1 += T * J; c2 += T * J; }   // diagonal zeros -> bin 0

        float w   = edg[tid + 1] - edg[tid];          // jnp.diff(edges)
        float den = __fmul_rn(NTOT, w);
        float px  = __fdiv_rn((float)c1, den);
        float qx  = __fdiv_rn((float)c2, den);
        float m   = (px + qx) * 0.5f;
        float lm  = logf(m + EPSF);
        float term = px * (logf(px + EPSF) - lm) + qx * (logf(qx + EPSF) - lm);
        sterm[tid] = term;
    }
    __syncthreads();
    if (tid == 0) {
        float acc = 0.0f;
        for (int i = 0; i < NBINS; ++i) acc += sterm[i];
        out[row] = acc * 0.5f;
    }
}

extern "C" void kernel_launch(void* const* d_in, const int* in_sizes, int n_in,
                              void* d_out, int out_size, void* d_ws, size_t ws_size,
                              hipStream_t stream) {
    const float* d1 = (const float*)d_in[0];
    const float* d2 = (const float*)d_in[1];
    float* out = (float*)d_out;
    jsd_kernel<<<BATCH, NTHREADS, 0, stream>>>(d1, d2, out);
}

// Round 4
// 44.855 us; speedup vs baseline: 2.7511x; 2.7511x over previous
//
#include <hip/hip_runtime.h>

// Problem constants (match the JAX reference)
constexpr int BATCH       = 256;
constexpr int T           = 100;
constexpr int J           = 32;
constexpr int EDGES       = 101;
constexpr int NBINS       = 100;
constexpr int NPAIR       = (J * (J - 1)) / 2;   // 496 unordered pairs
constexpr int PAIRS_TOTAL = T * NPAIR;           // 49600
constexpr int NPOINTS     = T * J;               // 3200 points per row
constexpr int ROW_FLOATS  = NPOINTS * 3;         // 9600 floats per row
constexpr int NREP        = 32;                  // histogram replicas
constexpr int NTHREADS    = 1024;                // 16 waves
constexpr int NWAVES      = NTHREADS / 64;
constexpr float EPSF      = 1e-8f;
constexpr float NTOT      = 102400.0f;           // T*J*J = counts.sum()

__global__ __launch_bounds__(NTHREADS)
void jsd_kernel(const float* __restrict__ g1all,
                const float* __restrict__ g2all,
                float* __restrict__ out)
{
#pragma clang fp contract(off)
    // Interleaved point layout, float2 units: point k = {x1y1, x2y2, z1z2}
    // -> 3x ds_read_b64 with imm offsets covers BOTH datasets.
    __shared__ float2 spt[NPOINTS * 3];              // 76,800 B
    __shared__ unsigned int hist[2][NREP][EDGES];    // 25,856 B
    __shared__ unsigned int lut[NPAIR];              //  1,984 B
    __shared__ float edg[EDGES];
    __shared__ float sred[NWAVES];
    __shared__ float sterm[NBINS];
    __shared__ float s_mx, s_invw;

    const int tid = threadIdx.x;
    const int row = blockIdx.x;
    const float* g1 = g1all + (size_t)row * ROW_FLOATS;
    const float* g2 = g2all + (size_t)row * ROW_FLOATS;

    // ---- Stage (interleaved), zero histograms, build premultiplied pair LUT.
    for (int k = tid; k < NPOINTS; k += NTHREADS) {
        float x1 = g1[3 * k], y1 = g1[3 * k + 1], z1 = g1[3 * k + 2];
        float x2 = g2[3 * k], y2 = g2[3 * k + 1], z2 = g2[3 * k + 2];
        spt[3 * k + 0] = make_float2(x1, y1);
        spt[3 * k + 1] = make_float2(x2, y2);
        spt[3 * k + 2] = make_float2(z1, z2);
    }
    for (int k = tid; k < 2 * NREP * EDGES; k += NTHREADS)
        (&hist[0][0][0])[k] = 0u;
    if (tid < J) {
        const int a = tid;
        int p = a * (2 * J - a - 1) / 2;             // triangular base
        for (int c = a + 1; c < J; ++c)
            lut[p++] = (unsigned)(((a * 3) << 16) | (c * 3));  // float2-unit offsets
    }
    __syncthreads();

    // ---- Pass A: max squared distance (sqrt monotone => sqrt(max)).
    float vmax = 0.0f;
    {
        int t0 = tid / NPAIR;                        // one-time div (magic mul)
        int r  = tid - t0 * NPAIR;
        int tb = t0 * (J * 3);                       // timestep base, float2 units
        for (int p = tid; p < PAIRS_TOTAL; p += NTHREADS) {
            const unsigned e = lut[r];
            const int ia = tb + (int)(e >> 16);
            const int ib = tb + (int)(e & 0xffffu);
            float2 a0 = spt[ia], a1 = spt[ia + 1], a2 = spt[ia + 2];
            float2 b0 = spt[ib], b1 = spt[ib + 1], b2 = spt[ib + 2];
            float dx1 = a0.x - b0.x, dy1 = a0.y - b0.y, dz1 = a2.x - b2.x;
            float s1 = dx1 * dx1 + dy1 * dy1 + dz1 * dz1;   // no FMA
            float dx2 = a1.x - b1.x, dy2 = a1.y - b1.y, dz2 = a2.y - b2.y;
            float s2 = dx2 * dx2 + dy2 * dy2 + dz2 * dz2;
            vmax = fmaxf(vmax, fmaxf(s1, s2));
            // p += 1024 == +2 timesteps, r += 32, at most one wrap (branch-free)
            r += 32;
            bool w = (r >= NPAIR);
            if (w) r -= NPAIR;
            tb += w ? (3 * J * 3) : (2 * J * 3);
        }
    }
    for (int off = 32; off > 0; off >>= 1)
        vmax = fmaxf(vmax, __shfl_down(vmax, off, 64));
    if ((tid & 63) == 0) sred[tid >> 6] = vmax;
    __syncthreads();
    if (tid == 0) {
        float m = sred[0];
        for (int w = 1; w < NWAVES; ++w) m = fmaxf(m, sred[w]);
        float mx = __fsqrt_rn(m);
        s_mx = mx;
        s_invw = 100.0f / mx;    // guess only — 2-probe fixup is exact
    }
    __syncthreads();
    const float mx   = s_mx;
    const float invw = s_invw;

    // edges[i] = mn*w0 + mx*w1, mn == 0 exactly (diagonal pairs) -> mx * w1[i];
    // w1[i] = (float)i * 0.01f, endpoint pinned to 1.0 (validated absmax 0.0).
    if (tid < EDGES) {
        float w1 = (tid == EDGES - 1) ? 1.0f : ((float)tid * 0.01f);
        edg[tid] = mx * w1;
    }
    __syncthreads();

    // ---- Pass B: recompute distances, branch-free exact binning, histogram.
    const int rep = tid & (NREP - 1);
    unsigned int* __restrict__ h1 = &hist[0][rep][0];
    unsigned int* __restrict__ h2 = &hist[1][rep][0];
    {
        int t0 = tid / NPAIR;
        int r  = tid - t0 * NPAIR;
        int tb = t0 * (J * 3);
        for (int p = tid; p < PAIRS_TOTAL; p += NTHREADS) {
            const unsigned e = lut[r];
            const int ia = tb + (int)(e >> 16);
            const int ib = tb + (int)(e & 0xffffu);
            float2 a0 = spt[ia], a1 = spt[ia + 1], a2 = spt[ia + 2];
            float2 b0 = spt[ib], b1 = spt[ib + 1], b2 = spt[ib + 2];
            float dx1 = a0.x - b0.x, dy1 = a0.y - b0.y, dz1 = a2.x - b2.x;
            float s1 = dx1 * dx1 + dy1 * dy1 + dz1 * dz1;
            float dx2 = a1.x - b1.x, dy2 = a1.y - b1.y, dz2 = a2.y - b2.y;
            float s2 = dx2 * dx2 + dy2 * dy2 + dz2 * dz2;

            const float x1 = __fsqrt_rn(s1);         // == reference's distance bitwise
            const float x2 = __fsqrt_rn(s2);

            // Exact searchsorted(right)-1: guess within +-1 (proven window),
            // two predicated f32 probes against the actual edges, clamp.
            int i1 = (int)(x1 * invw); i1 = i1 < 0 ? 0 : (i1 > 99 ? 99 : i1);
            int i2 = (int)(x2 * invw); i2 = i2 < 0 ? 0 : (i2 > 99 ? 99 : i2);
            i1 += (x1 >= edg[i1 + 1]) ? 1 : 0;
            i2 += (x2 >= edg[i2 + 1]) ? 1 : 0;
            i1 -= (x1 <  edg[i1])     ? 1 : 0;       // edg[0]=0 <= x: no underflow
            i2 -= (x2 <  edg[i2])     ? 1 : 0;
            i1 = i1 > 99 ? 99 : i1;
            i2 = i2 > 99 ? 99 : i2;

            atomicAdd(&h1[i1], 2u);                  // unordered pair -> weight 2
            atomicAdd(&h2[i2], 2u);

            r += 32;
            bool w = (r >= NPAIR);
            if (w) r -= NPAIR;
            tb += w ? (3 * J * 3) : (2 * J * 3);
        }
    }
    __syncthreads();

    // ---- Final: densities + JSD terms; serial 100-add sum (bit-exact).
    if (tid < NBINS) {
        unsigned int c1 = 0, c2 = 0;
        for (int rr = 0; rr < NREP; ++rr) { c1 += hist[0][rr][tid]; c2 += hist[1][rr][tid]; }
        if (tid == 0) { c1 += T * J; c2 += T * J; }  // diagonal zeros -> bin 0

        float w   = edg[tid + 1] - edg[tid];         // jnp.diff(edges)
        float den = __fmul_rn(NTOT, w);
        float px  = __fdiv_rn((float)c1, den);
        float qx  = __fdiv_rn((float)c2, den);
        float m   = (px + qx) * 0.5f;
        float lm  = logf(m + EPSF);
        float term = px * (logf(px + EPSF) - lm) + qx * (logf(qx + EPSF) - lm);
        sterm[tid] = term;
    }
    __syncthreads();
    if (tid == 0) {
        float acc = 0.0f;
        for (int i = 0; i < NBINS; ++i) acc += sterm[i];
        out[row] = acc * 0.5f;
    }
}

extern "C" void kernel_launch(void* const* d_in, const int* in_sizes, int n_in,
                              void* d_out, int out_size, void* d_ws, size_t ws_size,
                              hipStream_t stream) {
    const float* d1 = (const float*)d_in[0];
    const float* d2 = (const float*)d_in[1];
    float* out = (float*)d_out;
    jsd_kernel<<<BATCH, NTHREADS, 0, stream>>>(d1, d2, out);
}

// Round 5
// 44.552 us; speedup vs baseline: 2.7697x; 1.0068x over previous
//
#include <hip/hip_runtime.h>

// Problem constants (match the JAX reference)
constexpr int BATCH       = 256;
constexpr int T           = 100;
constexpr int J           = 32;
constexpr int EDGES       = 101;
constexpr int NBINS       = 100;
constexpr int NPAIR       = (J * (J - 1)) / 2;   // 496 unordered pairs
constexpr int PAIRS_TOTAL = T * NPAIR;           // 49600
constexpr int NPOINTS     = T * J;               // 3200 points per row
constexpr int ROW_FLOATS  = NPOINTS * 3;         // 9600 floats per row
constexpr int NREP        = 32;                  // histogram replicas
constexpr int NTHREADS    = 1024;                // 16 waves
constexpr int NWAVES      = NTHREADS / 64;
constexpr float EPSF      = 1e-8f;
constexpr float NTOT      = 102400.0f;           // T*J*J = counts.sum()

__global__ __launch_bounds__(NTHREADS)
void jsd_kernel(const float* __restrict__ g1all,
                const float* __restrict__ g2all,
                float* __restrict__ out)
{
#pragma clang fp contract(off)
    // Interleaved point layout, float2 units: point k = {x1y1, x2y2, z1z2}
    // -> 3x ds_read_b64 with imm offsets covers BOTH datasets.
    __shared__ float2 spt[NPOINTS * 3];              // 76,800 B
    __shared__ unsigned int hist[2][NREP][EDGES];    // 25,856 B
    __shared__ unsigned int lut[NPAIR];              //  1,984 B
    __shared__ float edg[EDGES];                     // epilogue widths only
    __shared__ float sred[NWAVES];
    __shared__ float sterm[NBINS];
    __shared__ float s_mx, s_invw;

    const int tid = threadIdx.x;
    const int row = blockIdx.x;
    const float* g1 = g1all + (size_t)row * ROW_FLOATS;
    const float* g2 = g2all + (size_t)row * ROW_FLOATS;

    // ---- Stage (interleaved), zero histograms, build premultiplied pair LUT.
    for (int k = tid; k < NPOINTS; k += NTHREADS) {
        float x1 = g1[3 * k], y1 = g1[3 * k + 1], z1 = g1[3 * k + 2];
        float x2 = g2[3 * k], y2 = g2[3 * k + 1], z2 = g2[3 * k + 2];
        spt[3 * k + 0] = make_float2(x1, y1);
        spt[3 * k + 1] = make_float2(x2, y2);
        spt[3 * k + 2] = make_float2(z1, z2);
    }
    for (int k = tid; k < 2 * NREP * EDGES; k += NTHREADS)
        (&hist[0][0][0])[k] = 0u;
    if (tid < J) {
        const int a = tid;
        int p = a * (2 * J - a - 1) / 2;             // triangular base
        for (int c = a + 1; c < J; ++c)
            lut[p++] = (unsigned)(((a * 3) << 16) | (c * 3));  // float2-unit offsets
    }
    __syncthreads();

    // ---- Pass A: max squared distance (sqrt monotone => sqrt(max)).
    float vmax = 0.0f;
    {
        int t0 = tid / NPAIR;                        // one-time div (magic mul)
        int r  = tid - t0 * NPAIR;
        int tb = t0 * (J * 3);                       // timestep base, float2 units
        for (int p = tid; p < PAIRS_TOTAL; p += NTHREADS) {
            const unsigned e = lut[r];
            const int ia = tb + (int)(e >> 16);
            const int ib = tb + (int)(e & 0xffffu);
            float2 a0 = spt[ia], a1 = spt[ia + 1], a2 = spt[ia + 2];
            float2 b0 = spt[ib], b1 = spt[ib + 1], b2 = spt[ib + 2];
            float dx1 = a0.x - b0.x, dy1 = a0.y - b0.y, dz1 = a2.x - b2.x;
            float s1 = dx1 * dx1 + dy1 * dy1 + dz1 * dz1;   // no FMA
            float dx2 = a1.x - b1.x, dy2 = a1.y - b1.y, dz2 = a2.y - b2.y;
            float s2 = dx2 * dx2 + dy2 * dy2 + dz2 * dz2;
            vmax = fmaxf(vmax, fmaxf(s1, s2));
            // p += 1024 == +2 timesteps, r += 32, at most one wrap (branch-free)
            r += 32;
            bool w = (r >= NPAIR);
            if (w) r -= NPAIR;
            tb += w ? (3 * J * 3) : (2 * J * 3);
        }
    }
    for (int off = 32; off > 0; off >>= 1)
        vmax = fmaxf(vmax, __shfl_down(vmax, off, 64));
    if ((tid & 63) == 0) sred[tid >> 6] = vmax;
    __syncthreads();
    if (tid == 0) {
        float m = sred[0];
        for (int w = 1; w < NWAVES; ++w) m = fmaxf(m, sred[w]);
        float mx = __fsqrt_rn(m);
        s_mx = mx;
        s_invw = 100.0f / mx;    // guess only — 2-probe fixup is exact
    }
    __syncthreads();
    const float mx   = s_mx;
    const float invw = s_invw;

    // edges[i] = mn*w0 + mx*w1, mn == 0 exactly (diagonal pairs) -> mx * w1[i];
    // w1[i] = (float)i * 0.01f, endpoint pinned to 1.0. Kept in LDS only for
    // the epilogue's bin widths; pass-B probes recompute edges in registers
    // (bitwise-identical for probe indices 1..99; index-100 mismatch harmless
    // under the final clamp-to-99, index 0 exact).
    if (tid < EDGES) {
        float w1 = (tid == EDGES - 1) ? 1.0f : ((float)tid * 0.01f);
        edg[tid] = mx * w1;
    }
    __syncthreads();

    // ---- Pass B: recompute distances, branch-free exact binning (VALU-only
    // probes), histogram.
    const int rep = tid & (NREP - 1);
    unsigned int* __restrict__ h1 = &hist[0][rep][0];
    unsigned int* __restrict__ h2 = &hist[1][rep][0];
    {
        int t0 = tid / NPAIR;
        int r  = tid - t0 * NPAIR;
        int tb = t0 * (J * 3);
        for (int p = tid; p < PAIRS_TOTAL; p += NTHREADS) {
            const unsigned e = lut[r];
            const int ia = tb + (int)(e >> 16);
            const int ib = tb + (int)(e & 0xffffu);
            float2 a0 = spt[ia], a1 = spt[ia + 1], a2 = spt[ia + 2];
            float2 b0 = spt[ib], b1 = spt[ib + 1], b2 = spt[ib + 2];
            float dx1 = a0.x - b0.x, dy1 = a0.y - b0.y, dz1 = a2.x - b2.x;
            float s1 = dx1 * dx1 + dy1 * dy1 + dz1 * dz1;
            float dx2 = a1.x - b1.x, dy2 = a1.y - b1.y, dz2 = a2.y - b2.y;
            float s2 = dx2 * dx2 + dy2 * dy2 + dz2 * dz2;

            const float x1 = __fsqrt_rn(s1);         // == reference's distance bitwise
            const float x2 = __fsqrt_rn(s2);

            // Exact searchsorted(right)-1: guess within +-1 (proven window),
            // two predicated probes vs register-recomputed edges, clamp.
            int i1 = (int)(x1 * invw); i1 = i1 < 0 ? 0 : (i1 > 99 ? 99 : i1);
            int i2 = (int)(x2 * invw); i2 = i2 < 0 ? 0 : (i2 > 99 ? 99 : i2);
            i1 += (x1 >= __fmul_rn(mx, __fmul_rn((float)(i1 + 1), 0.01f))) ? 1 : 0;
            i2 += (x2 >= __fmul_rn(mx, __fmul_rn((float)(i2 + 1), 0.01f))) ? 1 : 0;
            i1 -= (x1 <  __fmul_rn(mx, __fmul_rn((float)i1, 0.01f))) ? 1 : 0;
            i2 -= (x2 <  __fmul_rn(mx, __fmul_rn((float)i2, 0.01f))) ? 1 : 0;
            i1 = i1 > 99 ? 99 : i1;
            i2 = i2 > 99 ? 99 : i2;

            atomicAdd(&h1[i1], 2u);                  // unordered pair -> weight 2
            atomicAdd(&h2[i2], 2u);

            r += 32;
            bool w = (r >= NPAIR);
            if (w) r -= NPAIR;
            tb += w ? (3 * J * 3) : (2 * J * 3);
        }
    }
    __syncthreads();

    // ---- Final: densities + JSD terms; serial 100-add sum (bit-exact).
    if (tid < NBINS) {
        unsigned int c1 = 0, c2 = 0;
        for (int rr = 0; rr < NREP; ++rr) { c1 += hist[0][rr][tid]; c2 += hist[1][rr][tid]; }
        if (tid == 0) { c1 += T * J; c2 += T * J; }  // diagonal zeros -> bin 0

        float w   = edg[tid + 1] - edg[tid];         // jnp.diff(edges)
        float den = __fmul_rn(NTOT, w);
        float px  = __fdiv_rn((float)c1, den);
        float qx  = __fdiv_rn((float)c2, den);
        float m   = (px + qx) * 0.5f;
        float lm  = logf(m + EPSF);
        float term = px * (logf(px + EPSF) - lm) + qx * (logf(qx + EPSF) - lm);
        sterm[tid] = term;
    }
    __syncthreads();
    if (tid == 0) {
        float acc = 0.0f;
        for (int i = 0; i < NBINS; ++i) acc += sterm[i];
        out[row] = acc * 0.5f;
    }
}

extern "C" void kernel_launch(void* const* d_in, const int* in_sizes, int n_in,
                              void* d_out, int out_size, void* d_ws, size_t ws_size,
                              hipStream_t stream) {
    const float* d1 = (const float*)d_in[0];
    const float* d2 = (const float*)d_in[1];
    float* out = (float*)d_out;
    jsd_kernel<<<BATCH, NTHREADS, 0, stream>>>(d1, d2, out);
}

// Round 6
// 40.508 us; speedup vs baseline: 3.0463x; 1.0998x over previous
//
#include <hip/hip_runtime.h>

// Problem constants (match the JAX reference)
constexpr int BATCH       = 256;
constexpr int T           = 100;
constexpr int J           = 32;
constexpr int EDGES       = 101;
constexpr int NBINS       = 100;
constexpr int NPAIR       = (J * (J - 1)) / 2;   // 496 unordered pairs
constexpr int PAIRS_TOTAL = T * NPAIR;           // 49600
constexpr int NPOINTS     = T * J;               // 3200 points per row
constexpr int ROW_FLOATS  = NPOINTS * 3;         // 9600 floats per row
constexpr int NREP        = 32;                  // histogram replicas
constexpr int NTHREADS    = 1024;                // 16 waves
constexpr int NWAVES      = NTHREADS / 64;
constexpr float EPSF      = 1e-8f;
constexpr float NTOT      = 102400.0f;           // T*J*J = counts.sum()

// Raw v_sqrt_f32 (~1 ulp) — guess only; exact binning comes from threshold probes.
__device__ __forceinline__ float sqrt_approx(float s) {
    float r;
    asm("v_sqrt_f32 %0, %1" : "=v"(r) : "v"(s));
    return r;
}

__global__ __launch_bounds__(NTHREADS)
void jsd_kernel(const float* __restrict__ g1all,
                const float* __restrict__ g2all,
                float* __restrict__ out)
{
#pragma clang fp contract(off)
    // Interleaved point layout, float2 units: point k = {x1y1, x2y2, z1z2}
    // -> 3x ds_read_b64 with imm offsets covers BOTH datasets.
    __shared__ float2 spt[NPOINTS * 3];              // 76,800 B
    __shared__ unsigned int hist[2][NREP][EDGES];    // 25,856 B
    __shared__ unsigned int lut[NPAIR];              //  1,984 B
    __shared__ float edg[EDGES];                     // edges (epilogue widths)
    __shared__ float sqe[EDGES];                     // squared-domain thresholds m_i
    __shared__ float2 SQ2[NBINS];                    // {m_i, m_{i+1}} pairs
    __shared__ float sred[NWAVES];
    __shared__ float sterm[NBINS];
    __shared__ float s_mx, s_invw;

    const int tid = threadIdx.x;
    const int row = blockIdx.x;
    const float* g1 = g1all + (size_t)row * ROW_FLOATS;
    const float* g2 = g2all + (size_t)row * ROW_FLOATS;

    // ---- Stage (interleaved), zero histograms, build premultiplied pair LUT.
    for (int k = tid; k < NPOINTS; k += NTHREADS) {
        float x1 = g1[3 * k], y1 = g1[3 * k + 1], z1 = g1[3 * k + 2];
        float x2 = g2[3 * k], y2 = g2[3 * k + 1], z2 = g2[3 * k + 2];
        spt[3 * k + 0] = make_float2(x1, y1);
        spt[3 * k + 1] = make_float2(x2, y2);
        spt[3 * k + 2] = make_float2(z1, z2);
    }
    for (int k = tid; k < 2 * NREP * EDGES; k += NTHREADS)
        (&hist[0][0][0])[k] = 0u;
    if (tid < J) {
        const int a = tid;
        int p = a * (2 * J - a - 1) / 2;             // triangular base
        for (int c = a + 1; c < J; ++c)
            lut[p++] = (unsigned)(((a * 3) << 16) | (c * 3));  // float2-unit offsets
    }
    __syncthreads();

    // ---- Pass A: max squared distance (sqrt monotone => sqrt(max)).
    float vmax = 0.0f;
    {
        int t0 = tid / NPAIR;                        // one-time div (magic mul)
        int r  = tid - t0 * NPAIR;
        int tb = t0 * (J * 3);                       // timestep base, float2 units
        for (int p = tid; p < PAIRS_TOTAL; p += NTHREADS) {
            const unsigned e = lut[r];
            const int ia = tb + (int)(e >> 16);
            const int ib = tb + (int)(e & 0xffffu);
            float2 a0 = spt[ia], a1 = spt[ia + 1], a2 = spt[ia + 2];
            float2 b0 = spt[ib], b1 = spt[ib + 1], b2 = spt[ib + 2];
            float dx1 = a0.x - b0.x, dy1 = a0.y - b0.y, dz1 = a2.x - b2.x;
            float s1 = dx1 * dx1 + dy1 * dy1 + dz1 * dz1;   // no FMA
            float dx2 = a1.x - b1.x, dy2 = a1.y - b1.y, dz2 = a2.y - b2.y;
            float s2 = dx2 * dx2 + dy2 * dy2 + dz2 * dz2;
            vmax = fmaxf(vmax, fmaxf(s1, s2));
            // p += 1024 == +2 timesteps, r += 32, at most one wrap (branch-free)
            r += 32;
            bool w = (r >= NPAIR);
            if (w) r -= NPAIR;
            tb += w ? (3 * J * 3) : (2 * J * 3);
        }
    }
    for (int off = 32; off > 0; off >>= 1)
        vmax = fmaxf(vmax, __shfl_down(vmax, off, 64));
    if ((tid & 63) == 0) sred[tid >> 6] = vmax;
    __syncthreads();
    if (tid == 0) {
        float m = sred[0];
        for (int w = 1; w < NWAVES; ++w) m = fmaxf(m, sred[w]);
        float mx = __fsqrt_rn(m);
        s_mx = mx;
        s_invw = 100.0f / mx;    // guess only — threshold probes are exact
    }
    __syncthreads();
    const float mx   = s_mx;
    const float invw = s_invw;

    // edges[i] = mn*w0 + mx*w1, mn == 0 exactly (diagonal pairs) -> mx * w1[i];
    // w1[i] = (float)i * 0.01f, endpoint pinned to 1.0 (validated absmax 0.0).
    if (tid < EDGES) {
        float w1 = (tid == EDGES - 1) ? 1.0f : ((float)tid * 0.01f);
        edg[tid] = mx * w1;
    }
    __syncthreads();

    // Squared-domain thresholds: m_i = smallest float y >= 0 with RN(sqrt(y)) >= e[i].
    // Then  RN(sqrt(s)) >= e[i]  <=>  s >= m_i  — binning on s is EXACTLY the
    // reference's binning on the RN square-rooted distance (RN-sqrt monotone).
    // Start at RN(e*e) (radix-2: RN(sqrt(RN(e^2))) == e), ulp-walk to the edge.
    if (tid < EDGES) {
        float e = edg[tid];
        float y = 0.0f;                              // e[0] == 0 -> m_0 = 0
        if (tid > 0) {
            y = __fmul_rn(e, e);
            for (int it = 0; it < 4 && __fsqrt_rn(y) < e; ++it)
                y = __int_as_float(__float_as_int(y) + 1);   // safety (shouldn't fire)
            for (int it = 0; it < 8; ++it) {
                float py = __int_as_float(__float_as_int(y) - 1);
                if (__fsqrt_rn(py) >= e) y = py; else break;
            }
        }
        sqe[tid] = y;
    }
    __syncthreads();
    if (tid < NBINS) SQ2[tid] = make_float2(sqe[tid], sqe[tid + 1]);
    __syncthreads();

    // ---- Pass B: distances (squared only — no RN sqrt in the hot loop),
    // guess via raw v_sqrt, one b64 threshold-pair probe, histogram.
    const int rep = tid & (NREP - 1);
    unsigned int* __restrict__ h1 = &hist[0][rep][0];
    unsigned int* __restrict__ h2 = &hist[1][rep][0];
    {
        int t0 = tid / NPAIR;
        int r  = tid - t0 * NPAIR;
        int tb = t0 * (J * 3);
        for (int p = tid; p < PAIRS_TOTAL; p += NTHREADS) {
            const unsigned e = lut[r];
            const int ia = tb + (int)(e >> 16);
            const int ib = tb + (int)(e & 0xffffu);
            float2 a0 = spt[ia], a1 = spt[ia + 1], a2 = spt[ia + 2];
            float2 b0 = spt[ib], b1 = spt[ib + 1], b2 = spt[ib + 2];
            float dx1 = a0.x - b0.x, dy1 = a0.y - b0.y, dz1 = a2.x - b2.x;
            float s1 = dx1 * dx1 + dy1 * dy1 + dz1 * dz1;
            float dx2 = a1.x - b1.x, dy2 = a1.y - b1.y, dz2 = a2.y - b2.y;
            float s2 = dx2 * dx2 + dy2 * dy2 + dz2 * dz2;

            // Guess within +-1 (proven window: ~3e-5 index-units of error),
            // exact fixup via squared-domain threshold pair {m_i, m_(i+1)}.
            int i1 = (int)(sqrt_approx(s1) * invw);
            int i2 = (int)(sqrt_approx(s2) * invw);
            i1 = i1 < 0 ? 0 : (i1 > 99 ? 99 : i1);
            i2 = i2 < 0 ? 0 : (i2 > 99 ? 99 : i2);
            float2 t1 = SQ2[i1];
            float2 t2 = SQ2[i2];
            i1 += (s1 >= t1.y) ? 1 : 0;              // mutually exclusive with
            i1 -= (s1 <  t1.x) ? 1 : 0;              // the decrement (window +-1)
            i2 += (s2 >= t2.y) ? 1 : 0;
            i2 -= (s2 <  t2.x) ? 1 : 0;
            i1 = i1 > 99 ? 99 : i1;                  // == reference clip to NBINS-1
            i2 = i2 > 99 ? 99 : i2;

            atomicAdd(&h1[i1], 2u);                  // unordered pair -> weight 2
            atomicAdd(&h2[i2], 2u);

            r += 32;
            bool w = (r >= NPAIR);
            if (w) r -= NPAIR;
            tb += w ? (3 * J * 3) : (2 * J * 3);
        }
    }
    __syncthreads();

    // ---- Final: densities + JSD terms; serial 100-add sum (bit-exact).
    if (tid < NBINS) {
        unsigned int c1 = 0, c2 = 0;
        for (int rr = 0; rr < NREP; ++rr) { c1 += hist[0][rr][tid]; c2 += hist[1][rr][tid]; }
        if (tid == 0) { c1 += T * J; c2 += T * J; }  // diagonal zeros -> bin 0

        float w   = edg[tid + 1] - edg[tid];         // jnp.diff(edges)
        float den = __fmul_rn(NTOT, w);
        float px  = __fdiv_rn((float)c1, den);
        float qx  = __fdiv_rn((float)c2, den);
        float m   = (px + qx) * 0.5f;
        float lm  = logf(m + EPSF);
        float term = px * (logf(px + EPSF) - lm) + qx * (logf(qx + EPSF) - lm);
        sterm[tid] = term;
    }
    __syncthreads();
    if (tid == 0) {
        float acc = 0.0f;
        for (int i = 0; i < NBINS; ++i) acc += sterm[i];
        out[row] = acc * 0.5f;
    }
}

extern "C" void kernel_launch(void* const* d_in, const int* in_sizes, int n_in,
                              void* d_out, int out_size, void* d_ws, size_t ws_size,
                              hipStream_t stream) {
    const float* d1 = (const float*)d_in[0];
    const float* d2 = (const float*)d_in[1];
    float* out = (float*)d_out;
    jsd_kernel<<<BATCH, NTHREADS, 0, stream>>>(d1, d2, out);
}